// Round 13
// baseline (92.007 us; speedup 1.0000x reference)
//
#include <hip/hip_runtime.h>
#include <hip/hip_bf16.h>
#include <math.h>

#define B 8
#define N 4096
#define D 256
#define BN (B*N)
#define NSUP 64       // 64-row supers per batch (1 super == 1 mfma block tile)
#define NS1 65        // super bases + grand total
#define NR1 4097      // gran-1 prefix rows per batch (+ zero row 4096)
#define ALD 76        // As leading dim (ushorts): 152B rows -> 4-way wr / 2-way rd

typedef __attribute__((ext_vector_type(8))) short bf16x8;
typedef __attribute__((ext_vector_type(4))) float f32x4;

#define GLD16(src, dst) __builtin_amdgcn_global_load_lds( \
    (const __attribute__((address_space(1))) void*)(src), \
    (__attribute__((address_space(3))) void*)(dst), 16, 0, 0)

__device__ __forceinline__ ushort bf16_hi(float x) {
  __hip_bfloat16 h = __float2bfloat16(x);
  return *(ushort*)&h;
}
__device__ __forceinline__ ushort bf16_lo(float x) {
  __hip_bfloat16 h = __float2bfloat16(x);
  float hf = __bfloat162float(h);
  __hip_bfloat16 l = __float2bfloat16(x - hf);
  return *(ushort*)&l;
}

// ---------------- K1: f1/f2 dots + zero rank + W split (fused) -----------------
__global__ __launch_bounds__(256) void k_f1f2w(const float* __restrict__ seq,
    const float* __restrict__ w1, const float* __restrict__ b1,
    const float* __restrict__ w2, const float* __restrict__ b2,
    const float* __restrict__ W, float* __restrict__ f1, float* __restrict__ f2,
    int* __restrict__ rank, ushort* __restrict__ W3) {
  if (blockIdx.x >= BN/4) {                       // W -> W3t[n][768]=[Wh|Wl|Wh]
    int n = blockIdx.x - BN/4;
    int k = threadIdx.x;
    float x = W[(size_t)k * D + n];
    ushort hu = bf16_hi(x), lu = bf16_lo(x);
    W3[(size_t)n * 768 + k] = hu;
    W3[(size_t)n * 768 + 256 + k] = lu;
    W3[(size_t)n * 768 + 512 + k] = hu;
    return;
  }
  int wave = threadIdx.x >> 6;
  int lane = threadIdx.x & 63;
  long row = (long)blockIdx.x * 4 + wave;
  float4 v = ((const float4*)(seq + row * D))[lane];
  float4 a = ((const float4*)w1)[lane];
  float4 b = ((const float4*)w2)[lane];
  float s1 = v.x*a.x + v.y*a.y + v.z*a.z + v.w*a.w;
  float s2 = v.x*b.x + v.y*b.y + v.z*b.z + v.w*b.w;
  for (int off = 32; off; off >>= 1) {
    s1 += __shfl_xor(s1, off, 64);
    s2 += __shfl_xor(s2, off, 64);
  }
  if (lane == 0) {
    f1[row] = s1 + b1[0];
    f2[row] = s2 + b2[0];
    rank[row] = 0;
  }
}

// ---------------- K2a: partial rank counts (tiled O(N^2), 64-bit keys) ---------
__global__ __launch_bounds__(256) void k_rank_count(const float* __restrict__ f2,
    int* __restrict__ rank) {
  __shared__ unsigned long long skey[256];
  int b = blockIdx.z;
  int tid = threadIdx.x;
  const float* fb = f2 + (long)b * N;
  int p = blockIdx.y * 256 + tid;
  unsigned int up = __float_as_uint(fb[p]);
  up ^= (unsigned int)(((int)up >> 31) | 0x80000000);
  skey[tid] = ((unsigned long long)up << 12) | (unsigned)p;
  unsigned long long kj[4];
  int jbase = blockIdx.x * 1024;
  #pragma unroll
  for (int q = 0; q < 4; ++q) {
    int j = jbase + q * 256 + tid;
    unsigned int uj = __float_as_uint(fb[j]);
    uj ^= (unsigned int)(((int)uj >> 31) | 0x80000000);
    kj[q] = ((unsigned long long)uj << 12) | (unsigned)j;
  }
  __syncthreads();
  int c[4] = {0, 0, 0, 0};
  const ulonglong2* sk2 = (const ulonglong2*)skey;
  #pragma unroll 4
  for (int pp = 0; pp < 128; ++pp) {
    ulonglong2 kk = sk2[pp];
    #pragma unroll
    for (int q = 0; q < 4; ++q) {
      c[q] += (kk.x < kj[q]) ? 1 : 0;
      c[q] += (kk.y < kj[q]) ? 1 : 0;
    }
  }
  #pragma unroll
  for (int q = 0; q < 4; ++q)
    atomicAdd(&rank[(long)b * N + jbase + q * 256 + tid], c[q]);
}

// ---------------- K2b: scatter into sorted order -------------------------------
__global__ __launch_bounds__(256) void k_scatter(const float* __restrict__ f2,
    const int* __restrict__ rank, float* __restrict__ sF2, int* __restrict__ sIdx,
    float* __restrict__ e2lo, float* __restrict__ e2hi) {
  long idx = (long)blockIdx.x * 256 + threadIdx.x;
  int b = (int)(idx >> 12);
  int j = (int)(idx & (N - 1));
  float v = f2[idx];
  int cnt = rank[idx];
  long o = (long)b * N + cnt;
  sF2[o] = v;
  sIdx[o] = j;
  e2lo[o] = expf(0.01f * v);
  e2hi[o] = expf(v);
}

// ---------------- K3: split-bf16 MFMA GEMM + fused prefix epilogue -------------
// R8-proven skeleton + double-buffered Bs: per step S1 drains loads issued a
// FULL step ago (cheap); new Bs loads issue after S2 and land under the MFMA.
// As ALD=76 fixes the 8-way staging-write conflict (152B row stride).
__global__ __launch_bounds__(256) void k_mfma(const float* __restrict__ seq,
    const int* __restrict__ sIdx, const ushort* __restrict__ W3,
    const float* __restrict__ e2lo, const float* __restrict__ e2hi,
    float* __restrict__ Rel, float* __restrict__ Zrel,
    float* __restrict__ SupBaseLo, float* __restrict__ SupBaseHi,
    float* __restrict__ SupZlo, float* __restrict__ SupZhi) {
  __shared__ __align__(16) char smem[64*ALD*2 + 2*256*64*2];  // 9.5KB As + 64KB Bs[2]
  ushort (*As)[ALD] = (ushort(*)[ALD])smem;
  ushort (*BsBuf)[64] = (ushort(*)[64])(smem + 64 * ALD * 2); // [512][64]; buf c at rows c*256
  int tid = threadIdx.x;
  int wid = tid >> 6, lane = tid & 63;
  int mBase = blockIdx.x * 64;
  int b = mBase >> 12;
  int ar = tid >> 2, aq = tid & 3;
  const float* aSrc = seq + (((size_t)(b << 12)) + sIdx[mBase + ar]) * D + aq * 16;
  int lr = lane >> 3;
  int lcSw = (((lane & 7) ^ (lr & 7))) * 8;
  int wr = wid >> 1, wc = wid & 1, g = lane >> 4, r16 = lane & 15;
  int bswz = r16 & 7;

  f32x4 acc[2][8];
  #pragma unroll
  for (int m = 0; m < 2; ++m)
    #pragma unroll
    for (int n = 0; n < 8; ++n) {
      acc[m][n][0] = 0.f; acc[m][n][1] = 0.f; acc[m][n][2] = 0.f; acc[m][n][3] = 0.f;
    }

  // prologue: ou(kt=0), Bs[0](kt=0) in flight, xvA = acol(64)
  float4 xvA[4], xvB[4];
  ushort ou[16];
  #pragma unroll
  for (int i = 0; i < 4; ++i) xvA[i] = *(const float4*)(aSrc + i * 4);     // acol 0
  #pragma unroll
  for (int i = 0; i < 4; ++i) {
    ou[i*4+0] = bf16_hi(xvA[i].x); ou[i*4+1] = bf16_hi(xvA[i].y);
    ou[i*4+2] = bf16_hi(xvA[i].z); ou[i*4+3] = bf16_hi(xvA[i].w);
  }
  #pragma unroll
  for (int q = 0; q < 8; ++q) {
    int r0 = q * 32 + wid * 8;
    GLD16(W3 + (size_t)(r0 + lr) * 768 + 0 + lcSw, &BsBuf[r0][0]);
  }
  #pragma unroll
  for (int i = 0; i < 4; ++i) xvA[i] = *(const float4*)(aSrc + 64 + i * 4); // acol 64

  for (int kt = 0; kt < 768; kt += 64) {
    int cur = (kt >> 6) & 1;
    __syncthreads();                       // S1: Bs[cur] (issued a step ago) drained
    #pragma unroll
    for (int i = 0; i < 4; ++i)
      *(ushort4*)&As[ar][aq * 16 + i * 4] =
          make_ushort4(ou[i*4+0], ou[i*4+1], ou[i*4+2], ou[i*4+3]);
    __syncthreads();                       // S2: As visible; nothing new outstanding
    if (kt < 704) {                        // next Bs into other buffer (lands under MFMA)
      int nkt = kt + 64;
      #pragma unroll
      for (int q = 0; q < 8; ++q) {
        int r0 = q * 32 + wid * 8;
        GLD16(W3 + (size_t)(r0 + lr) * 768 + nkt + lcSw, &BsBuf[(cur ^ 1) * 256 + r0][0]);
      }
    }
    if (kt <= 576) {                       // A prefetch two steps ahead
      int nacol = (kt + 128) & 255;
      #pragma unroll
      for (int i = 0; i < 4; ++i) xvB[i] = *(const float4*)(aSrc + nacol + i * 4);
    }
    #pragma unroll
    for (int kk = 0; kk < 64; kk += 32) {
      bf16x8 av[2], bv[8];
      #pragma unroll
      for (int m = 0; m < 2; ++m)
        av[m] = *(const bf16x8*)&As[wr*32 + m*16 + r16][kk + g*8];
      int jb = (kk >> 3) + g;
      int jj = jb ^ bswz;
      #pragma unroll
      for (int n = 0; n < 8; ++n) {
        int row = cur * 256 + wc*128 + n*16 + r16;
        bv[n] = *(const bf16x8*)((const char*)BsBuf + row * 128 + jj * 16);
      }
      #pragma unroll
      for (int m = 0; m < 2; ++m)
        #pragma unroll
        for (int n = 0; n < 8; ++n)
          acc[m][n] = __builtin_amdgcn_mfma_f32_16x16x32_bf16(av[m], bv[n], acc[m][n], 0, 0, 0);
    }
    if (kt < 704) {                        // cvt for kt+64 (xvA landed during MFMA)
      if (kt + 64 < 512) {
        #pragma unroll
        for (int i = 0; i < 4; ++i) {
          ou[i*4+0] = bf16_hi(xvA[i].x); ou[i*4+1] = bf16_hi(xvA[i].y);
          ou[i*4+2] = bf16_hi(xvA[i].z); ou[i*4+3] = bf16_hi(xvA[i].w);
        }
      } else {
        #pragma unroll
        for (int i = 0; i < 4; ++i) {
          ou[i*4+0] = bf16_lo(xvA[i].x); ou[i*4+1] = bf16_lo(xvA[i].y);
          ou[i*4+2] = bf16_lo(xvA[i].z); ou[i*4+3] = bf16_lo(xvA[i].w);
        }
      }
      #pragma unroll
      for (int i = 0; i < 4; ++i) xvA[i] = xvB[i];
    }
  }

  // ---- epilogue: LDS transpose + within-super exclusive prefix (gran-1) ----
  __syncthreads();
  float (*Vt)[256] = (float(*)[256])smem;
  // full 5-bit swizzle: cswz = (g<<2)|((g&1)<<4) -> 32 banks x 2-way (free)
  int cswz = (g << 2) | ((g & 1) << 4);
  #pragma unroll
  for (int m = 0; m < 2; ++m)
    #pragma unroll
    for (int n = 0; n < 8; ++n) {
      int col = (wc*128 + n*16 + r16) ^ cswz;
      #pragma unroll
      for (int j = 0; j < 4; ++j)
        Vt[wr*32 + m*16 + g*4 + j][col] = acc[m][n][j];
    }
  __syncthreads();
  int d = tid;
  int s = (mBase >> 6) & 63;
  size_t rb = (size_t)mBase;
  float rl = 0.f, rh = 0.f;
  float* pR = Rel + ((size_t)b * NR1 + (size_t)s * 64) * 512 + 2 * d;  // [k][d][2]
  #pragma unroll 8
  for (int r = 0; r < 64; ++r) {
    int gr = (r >> 2) & 3;
    int rsw = (gr << 2) | ((gr & 1) << 4);
    float wlo = e2lo[rb + r], whi = e2hi[rb + r];
    float v = Vt[r][d ^ rsw];
    float2 pr; pr.x = rl; pr.y = rh;
    *(float2*)(pR + (size_t)r * 512) = pr;
    rl += wlo * v; rh += whi * v;
  }
  SupBaseLo[((size_t)b * NS1 + s) * D + d] = rl;
  SupBaseHi[((size_t)b * NS1 + s) * D + d] = rh;
  if (tid == 0) {
    float z = 0.f;
    #pragma unroll 8
    for (int r = 0; r < 64; ++r) { Zrel[((size_t)b * NR1 + s*64 + r) * 2] = z; z += e2lo[rb + r]; }
    SupZlo[b*NS1+s] = z;
  } else if (tid == 64) {
    float z = 0.f;
    #pragma unroll 8
    for (int r = 0; r < 64; ++r) { Zrel[((size_t)b * NR1 + s*64 + r) * 2 + 1] = z; z += e2hi[rb + r]; }
    SupZhi[b*NS1+s] = z;
  }
}

// ---------------- K4: scan 64 super bases (exclusive) + zero rows --------------
__global__ __launch_bounds__(256) void k_supscan(float* __restrict__ SupBaseLo,
    float* __restrict__ SupBaseHi, float* __restrict__ SupZlo,
    float* __restrict__ SupZhi, float* __restrict__ Rel, float* __restrict__ Zrel) {
  int b = blockIdx.x, t = threadIdx.x;
  if (t < 64) {
    float4* lo = (float4*)SupBaseLo + (size_t)b * NS1 * 64 + t;
    float4* hi = (float4*)SupBaseHi + (size_t)b * NS1 * 64 + t;
    float4 rl = {0,0,0,0}, rh = {0,0,0,0};
    for (int s = 0; s < NSUP; s += 8) {
      float4 tl[8], th[8];
      #pragma unroll
      for (int u = 0; u < 8; ++u) { tl[u] = lo[(size_t)(s+u)*64]; th[u] = hi[(size_t)(s+u)*64]; }
      #pragma unroll
      for (int u = 0; u < 8; ++u) {
        lo[(size_t)(s+u)*64] = rl; hi[(size_t)(s+u)*64] = rh;
        rl.x+=tl[u].x; rl.y+=tl[u].y; rl.z+=tl[u].z; rl.w+=tl[u].w;
        rh.x+=th[u].x; rh.y+=th[u].y; rh.z+=th[u].z; rh.w+=th[u].w;
      }
    }
    lo[(size_t)NSUP*64] = rl;     // grand totals
    hi[(size_t)NSUP*64] = rh;
  } else if (t < 192) {
    float4 z = {0,0,0,0};
    ((float4*)(Rel + ((size_t)b * NR1 + 4096) * 512))[t - 64] = z;
  } else if (t == 192) {
    float r = 0.f;
    for (int s = 0; s < NSUP; ++s) { float x = SupZlo[b*NS1+s]; SupZlo[b*NS1+s] = r; r += x; }
    SupZlo[b*NS1+NSUP] = r;
    Zrel[((size_t)b * NR1 + 4096) * 2] = 0.f;
  } else if (t == 193) {
    float r = 0.f;
    for (int s = 0; s < NSUP; ++s) { float x = SupZhi[b*NS1+s]; SupZhi[b*NS1+s] = r; r += x; }
    SupZhi[b*NS1+NSUP] = r;
    Zrel[((size_t)b * NR1 + 4096) * 2 + 1] = 0.f;
  }
}

// ---------------- K5: combine (binary search + gran-1 prefix) ------------------
__global__ __launch_bounds__(256) void k_combine2(const float* __restrict__ f1,
    const float* __restrict__ sF2, const float* __restrict__ Rel,
    const float* __restrict__ SupBaseLo, const float* __restrict__ SupBaseHi,
    const float* __restrict__ SupZlo, const float* __restrict__ SupZhi,
    const float* __restrict__ Zrel,
    const float* __restrict__ bias, float* __restrict__ out) {
  int wid = threadIdx.x >> 6, lane = threadIdx.x & 63;
  size_t i = (size_t)blockIdx.x * 4 + wid;
  int b = (int)(i >> 12);
  float f1v = f1[i];
  const float* sb = sF2 + ((size_t)b << 12);
  float t = -f1v;
  int lo = 0, hi = N;
  while (lo < hi) { int mid = (lo + hi) >> 1; if (sb[mid] <= t) lo = mid + 1; else hi = mid; }
  int k = lo;
  int s = k >> 6;
  float a = expf(f1v), cc = expf(0.01f * f1v);
  const float* rrow = Rel + ((size_t)b * NR1 + k) * 512;   // [d][2] interleaved
  float4 q0 = ((const float4*)rrow)[2*lane];      // lo0,hi0,lo1,hi1
  float4 q1 = ((const float4*)rrow)[2*lane + 1];  // lo2,hi2,lo3,hi3
  float4 sblo = ((const float4*)SupBaseLo)[((size_t)b * NS1 + s) * 64 + lane];
  float4 sbhi = ((const float4*)SupBaseHi)[((size_t)b * NS1 + s) * 64 + lane];
  float4 pht  = ((const float4*)SupBaseHi)[((size_t)b * NS1 + NSUP) * 64 + lane];
  float2 z2 = *(const float2*)(Zrel + ((size_t)b * NR1 + k) * 2);
  float Zlo = SupZlo[b*NS1+s] + z2.x;
  float Zhi = SupZhi[b*NS1+NSUP] - SupZhi[b*NS1+s] - z2.y;
  float Z = a * Zhi + cc * Zlo;
  float rz = 1.f / Z;
  float bs = bias[0];
  float4 o4;
  o4.x = fmaxf((a*(pht.x - sbhi.x - q0.y) + cc*(sblo.x + q0.x)) * rz + bs, 0.f);
  o4.y = fmaxf((a*(pht.y - sbhi.y - q0.w) + cc*(sblo.y + q0.z)) * rz + bs, 0.f);
  o4.z = fmaxf((a*(pht.z - sbhi.z - q1.y) + cc*(sblo.z + q1.x)) * rz + bs, 0.f);
  o4.w = fmaxf((a*(pht.w - sbhi.w - q1.w) + cc*(sblo.w + q1.z)) * rz + bs, 0.f);
  ((float4*)out)[i * 64 + lane] = o4;
}

// ---------------- launch -------------------------------------------------------
extern "C" void kernel_launch(void* const* d_in, const int* in_sizes, int n_in,
                              void* d_out, int out_size, void* d_ws, size_t ws_size,
                              hipStream_t stream) {
  const float* seq  = (const float*)d_in[0];
  const float* Wf   = (const float*)d_in[1];
  const float* w1   = (const float*)d_in[2];
  const float* b1   = (const float*)d_in[3];
  const float* w2   = (const float*)d_in[4];
  const float* b2   = (const float*)d_in[5];
  const float* bias = (const float*)d_in[6];
  float* out = (float*)d_out;

  size_t needFloats = (size_t)7*BN + (size_t)B*NR1*512 + 2*(size_t)B*NS1*D
                    + 2*(size_t)B*NS1 + 2*(size_t)B*NR1;
  size_t need = needFloats * 4 + (size_t)256 * 768 * 2;
  if (ws_size < need) return;

  float* f1   = (float*)d_ws;
  float* f2   = f1 + BN;
  float* sF2  = f2 + BN;
  float* e2lo = sF2 + BN;
  float* e2hi = e2lo + BN;
  int* sIdx   = (int*)(e2hi + BN);
  int* rank   = sIdx + BN;
  float* Rel  = (float*)(rank + BN);               // [b][k][d][2] interleaved
  float* SupBaseLo = Rel + (size_t)B * NR1 * 512;
  float* SupBaseHi = SupBaseLo + (size_t)B * NS1 * D;
  float* SupZlo = SupBaseHi + (size_t)B * NS1 * D;
  float* SupZhi = SupZlo + B * NS1;
  float* Zrel   = SupZhi + B * NS1;                // [b][k][2]
  ushort* W3 = (ushort*)(Zrel + 2 * (size_t)B * NR1);

  k_f1f2w<<<dim3(BN/4 + 256), 256, 0, stream>>>(seq, w1, b1, w2, b2, Wf,
      f1, f2, rank, W3);
  k_rank_count<<<dim3(N/1024, N/256, B), 256, 0, stream>>>(f2, rank);
  k_scatter<<<dim3(BN/256), 256, 0, stream>>>(f2, rank, sF2, sIdx, e2lo, e2hi);
  k_mfma<<<dim3(BN/64), 256, 0, stream>>>(seq, sIdx, W3, e2lo, e2hi,
      Rel, Zrel, SupBaseLo, SupBaseHi, SupZlo, SupZhi);
  k_supscan<<<dim3(B), 256, 0, stream>>>(SupBaseLo, SupBaseHi, SupZlo, SupZhi,
      Rel, Zrel);
  k_combine2<<<dim3(BN/4), 256, 0, stream>>>(f1, sF2, Rel,
      SupBaseLo, SupBaseHi, SupZlo, SupZhi, Zrel, bias, out);
}

// Round 14
// 88.110 us; speedup vs baseline: 1.0442x; 1.0442x over previous
//
#include <hip/hip_runtime.h>
#include <hip/hip_bf16.h>
#include <math.h>

#define B 8
#define N 4096
#define D 256
#define BN (B*N)
#define NSUP 64       // 64-row supers per batch (1 super == 1 mfma block tile)
#define NS1 65        // super bases + grand total
#define NR1 4097      // gran-1 prefix rows per batch (+ zero row 4096)

typedef __attribute__((ext_vector_type(8))) short bf16x8;
typedef __attribute__((ext_vector_type(4))) float f32x4;

#define GLD16(src, dst) __builtin_amdgcn_global_load_lds( \
    (const __attribute__((address_space(1))) void*)(src), \
    (__attribute__((address_space(3))) void*)(dst), 16, 0, 0)

__device__ __forceinline__ ushort bf16_hi(float x) {
  __hip_bfloat16 h = __float2bfloat16(x);
  return *(ushort*)&h;
}
__device__ __forceinline__ ushort bf16_lo(float x) {
  __hip_bfloat16 h = __float2bfloat16(x);
  float hf = __bfloat162float(h);
  __hip_bfloat16 l = __float2bfloat16(x - hf);
  return *(ushort*)&l;
}

// ---------------- K1: f1/f2 dots + zero rank + W split (fused) -----------------
__global__ __launch_bounds__(256) void k_f1f2w(const float* __restrict__ seq,
    const float* __restrict__ w1, const float* __restrict__ b1,
    const float* __restrict__ w2, const float* __restrict__ b2,
    const float* __restrict__ W, float* __restrict__ f1, float* __restrict__ f2,
    int* __restrict__ rank, ushort* __restrict__ W3) {
  if (blockIdx.x >= BN/4) {                       // W -> W3t[n][768]=[Wh|Wl|Wh]
    int n = blockIdx.x - BN/4;
    int k = threadIdx.x;
    float x = W[(size_t)k * D + n];
    ushort hu = bf16_hi(x), lu = bf16_lo(x);
    W3[(size_t)n * 768 + k] = hu;
    W3[(size_t)n * 768 + 256 + k] = lu;
    W3[(size_t)n * 768 + 512 + k] = hu;
    return;
  }
  int wave = threadIdx.x >> 6;
  int lane = threadIdx.x & 63;
  long row = (long)blockIdx.x * 4 + wave;
  float4 v = ((const float4*)(seq + row * D))[lane];
  float4 a = ((const float4*)w1)[lane];
  float4 b = ((const float4*)w2)[lane];
  float s1 = v.x*a.x + v.y*a.y + v.z*a.z + v.w*a.w;
  float s2 = v.x*b.x + v.y*b.y + v.z*b.z + v.w*b.w;
  for (int off = 32; off; off >>= 1) {
    s1 += __shfl_xor(s1, off, 64);
    s2 += __shfl_xor(s2, off, 64);
  }
  if (lane == 0) {
    f1[row] = s1 + b1[0];
    f2[row] = s2 + b2[0];
    rank[row] = 0;
  }
}

// ---------------- K2a: partial rank counts (tiled O(N^2), 64-bit keys) ---------
__global__ __launch_bounds__(256) void k_rank_count(const float* __restrict__ f2,
    int* __restrict__ rank) {
  __shared__ unsigned long long skey[256];
  int b = blockIdx.z;
  int tid = threadIdx.x;
  const float* fb = f2 + (long)b * N;
  int p = blockIdx.y * 256 + tid;
  unsigned int up = __float_as_uint(fb[p]);
  up ^= (unsigned int)(((int)up >> 31) | 0x80000000);
  skey[tid] = ((unsigned long long)up << 12) | (unsigned)p;
  unsigned long long kj[4];
  int jbase = blockIdx.x * 1024;
  #pragma unroll
  for (int q = 0; q < 4; ++q) {
    int j = jbase + q * 256 + tid;
    unsigned int uj = __float_as_uint(fb[j]);
    uj ^= (unsigned int)(((int)uj >> 31) | 0x80000000);
    kj[q] = ((unsigned long long)uj << 12) | (unsigned)j;
  }
  __syncthreads();
  int c[4] = {0, 0, 0, 0};
  const ulonglong2* sk2 = (const ulonglong2*)skey;
  #pragma unroll 4
  for (int pp = 0; pp < 128; ++pp) {
    ulonglong2 kk = sk2[pp];
    #pragma unroll
    for (int q = 0; q < 4; ++q) {
      c[q] += (kk.x < kj[q]) ? 1 : 0;
      c[q] += (kk.y < kj[q]) ? 1 : 0;
    }
  }
  #pragma unroll
  for (int q = 0; q < 4; ++q)
    atomicAdd(&rank[(long)b * N + jbase + q * 256 + tid], c[q]);
}

// ---------------- K2b: scatter into sorted order -------------------------------
__global__ __launch_bounds__(256) void k_scatter(const float* __restrict__ f2,
    const int* __restrict__ rank, float* __restrict__ sF2, int* __restrict__ sIdx,
    float* __restrict__ e2lo, float* __restrict__ e2hi) {
  long idx = (long)blockIdx.x * 256 + threadIdx.x;
  int b = (int)(idx >> 12);
  int j = (int)(idx & (N - 1));
  float v = f2[idx];
  int cnt = rank[idx];
  long o = (long)b * N + cnt;
  sF2[o] = v;
  sIdx[o] = j;
  e2lo[o] = expf(0.01f * v);
  e2hi[o] = expf(v);
}

// ---------------- K3: split-bf16 MFMA GEMM + fused prefix epilogue -------------
// R11-proven skeleton; only in-loop ORDER changed: GLD16 issues first after S1,
// then As-store + next-step cvt + xv prefetch sit in the load shadow before S2.
// (R12 dbuf regressed; R10 work-removal regressed; barriers/buffers unchanged.)
__global__ __launch_bounds__(256) void k_mfma(const float* __restrict__ seq,
    const int* __restrict__ sIdx, const ushort* __restrict__ W3,
    const float* __restrict__ e2lo, const float* __restrict__ e2hi,
    float* __restrict__ Rel, float* __restrict__ Zrel,
    float* __restrict__ SupBaseLo, float* __restrict__ SupBaseHi,
    float* __restrict__ SupZlo, float* __restrict__ SupZhi) {
  __shared__ __align__(16) char smem[64 * 256 * 4];   // 64KB union
  ushort (*As)[72] = (ushort(*)[72])smem;
  ushort (*Bs)[64] = (ushort(*)[64])(smem + 64 * 72 * 2);
  int tid = threadIdx.x;
  int wid = tid >> 6, lane = tid & 63;
  int mBase = blockIdx.x * 64;
  int b = mBase >> 12;
  int ar = tid >> 2, aq = tid & 3;
  const float* aSrc = seq + (((size_t)(b << 12)) + sIdx[mBase + ar]) * D + aq * 16;
  int lr = lane >> 3;
  int lcSw = (((lane & 7) ^ (lr & 7))) * 8;
  int wr = wid >> 1, wc = wid & 1, g = lane >> 4, r16 = lane & 15;
  int bswz = r16 & 7;

  f32x4 acc[2][8];
  #pragma unroll
  for (int m = 0; m < 2; ++m)
    #pragma unroll
    for (int n = 0; n < 8; ++n) {
      acc[m][n][0] = 0.f; acc[m][n][1] = 0.f; acc[m][n][2] = 0.f; acc[m][n][3] = 0.f;
    }

  // prologue: ou = cvt(cols 0..63, hi); xv = cols 64..127 (raw)
  float4 xv[4];
  ushort ou[16];
  #pragma unroll
  for (int i = 0; i < 4; ++i) xv[i] = *(const float4*)(aSrc + i * 4);
  #pragma unroll
  for (int i = 0; i < 4; ++i) {
    ou[i*4+0] = bf16_hi(xv[i].x); ou[i*4+1] = bf16_hi(xv[i].y);
    ou[i*4+2] = bf16_hi(xv[i].z); ou[i*4+3] = bf16_hi(xv[i].w);
  }
  #pragma unroll
  for (int i = 0; i < 4; ++i) xv[i] = *(const float4*)(aSrc + 64 + i * 4);

  for (int kt = 0; kt < 768; kt += 64) {
    __syncthreads();                       // S1: previous MFMA done with As/Bs
    #pragma unroll
    for (int q = 0; q < 8; ++q) {          // issue Bs(kt) FIRST
      int r0 = q * 32 + wid * 8;
      GLD16(W3 + (size_t)(r0 + lr) * 768 + kt + lcSw, &Bs[r0][0]);
    }
    #pragma unroll
    for (int i = 0; i < 4; ++i)            // As store in the load shadow
      *(ushort4*)&As[ar][aq * 16 + i * 4] =
          make_ushort4(ou[i*4+0], ou[i*4+1], ou[i*4+2], ou[i*4+3]);
    if (kt < 704) {                        // cvt for kt+64 (also in shadow)
      if (kt + 64 < 512) {
        #pragma unroll
        for (int i = 0; i < 4; ++i) {
          ou[i*4+0] = bf16_hi(xv[i].x); ou[i*4+1] = bf16_hi(xv[i].y);
          ou[i*4+2] = bf16_hi(xv[i].z); ou[i*4+3] = bf16_hi(xv[i].w);
        }
      } else {
        #pragma unroll
        for (int i = 0; i < 4; ++i) {
          ou[i*4+0] = bf16_lo(xv[i].x); ou[i*4+1] = bf16_lo(xv[i].y);
          ou[i*4+2] = bf16_lo(xv[i].z); ou[i*4+3] = bf16_lo(xv[i].w);
        }
      }
    }
    if (kt <= 576) {                       // xv prefetch for kt+128 (issue only)
      int nacol = (kt + 128) & 255;
      #pragma unroll
      for (int i = 0; i < 4; ++i) xv[i] = *(const float4*)(aSrc + nacol + i * 4);
    }
    __syncthreads();                       // S2: Bs(kt) + As visible
    #pragma unroll
    for (int kk = 0; kk < 64; kk += 32) {
      bf16x8 av[2], bv[8];
      #pragma unroll
      for (int m = 0; m < 2; ++m)
        av[m] = *(const bf16x8*)&As[wr*32 + m*16 + r16][kk + g*8];
      int jb = (kk >> 3) + g;
      int jj = jb ^ bswz;
      #pragma unroll
      for (int n = 0; n < 8; ++n) {
        int row = wc*128 + n*16 + r16;
        bv[n] = *(const bf16x8*)((const char*)Bs + row * 128 + jj * 16);
      }
      #pragma unroll
      for (int m = 0; m < 2; ++m)
        #pragma unroll
        for (int n = 0; n < 8; ++n)
          acc[m][n] = __builtin_amdgcn_mfma_f32_16x16x32_bf16(av[m], bv[n], acc[m][n], 0, 0, 0);
    }
  }

  // ---- epilogue: LDS transpose + within-super exclusive prefix (gran-1) ----
  __syncthreads();
  float (*Vt)[256] = (float(*)[256])smem;
  // full 5-bit swizzle: cswz = (g<<2)|((g&1)<<4) -> 32 banks x 2-way (free)
  int cswz = (g << 2) | ((g & 1) << 4);
  #pragma unroll
  for (int m = 0; m < 2; ++m)
    #pragma unroll
    for (int n = 0; n < 8; ++n) {
      int col = (wc*128 + n*16 + r16) ^ cswz;
      #pragma unroll
      for (int j = 0; j < 4; ++j)
        Vt[wr*32 + m*16 + g*4 + j][col] = acc[m][n][j];
    }
  __syncthreads();
  int d = tid;
  int s = (mBase >> 6) & 63;
  size_t rb = (size_t)mBase;
  float rl = 0.f, rh = 0.f;
  float* pR = Rel + ((size_t)b * NR1 + (size_t)s * 64) * 512 + 2 * d;  // [k][d][2]
  #pragma unroll 8
  for (int r = 0; r < 64; ++r) {
    int gr = (r >> 2) & 3;
    int rsw = (gr << 2) | ((gr & 1) << 4);
    float wlo = e2lo[rb + r], whi = e2hi[rb + r];
    float v = Vt[r][d ^ rsw];
    float2 pr; pr.x = rl; pr.y = rh;
    *(float2*)(pR + (size_t)r * 512) = pr;
    rl += wlo * v; rh += whi * v;
  }
  SupBaseLo[((size_t)b * NS1 + s) * D + d] = rl;
  SupBaseHi[((size_t)b * NS1 + s) * D + d] = rh;
  if (tid == 0) {
    float z = 0.f;
    #pragma unroll 8
    for (int r = 0; r < 64; ++r) { Zrel[((size_t)b * NR1 + s*64 + r) * 2] = z; z += e2lo[rb + r]; }
    SupZlo[b*NS1+s] = z;
  } else if (tid == 64) {
    float z = 0.f;
    #pragma unroll 8
    for (int r = 0; r < 64; ++r) { Zrel[((size_t)b * NR1 + s*64 + r) * 2 + 1] = z; z += e2hi[rb + r]; }
    SupZhi[b*NS1+s] = z;
  }
}

// ---------------- K4: scan 64 super bases (exclusive) + zero rows --------------
__global__ __launch_bounds__(256) void k_supscan(float* __restrict__ SupBaseLo,
    float* __restrict__ SupBaseHi, float* __restrict__ SupZlo,
    float* __restrict__ SupZhi, float* __restrict__ Rel, float* __restrict__ Zrel) {
  int b = blockIdx.x, t = threadIdx.x;
  if (t < 64) {
    float4* lo = (float4*)SupBaseLo + (size_t)b * NS1 * 64 + t;
    float4* hi = (float4*)SupBaseHi + (size_t)b * NS1 * 64 + t;
    float4 rl = {0,0,0,0}, rh = {0,0,0,0};
    for (int s = 0; s < NSUP; s += 8) {
      float4 tl[8], th[8];
      #pragma unroll
      for (int u = 0; u < 8; ++u) { tl[u] = lo[(size_t)(s+u)*64]; th[u] = hi[(size_t)(s+u)*64]; }
      #pragma unroll
      for (int u = 0; u < 8; ++u) {
        lo[(size_t)(s+u)*64] = rl; hi[(size_t)(s+u)*64] = rh;
        rl.x+=tl[u].x; rl.y+=tl[u].y; rl.z+=tl[u].z; rl.w+=tl[u].w;
        rh.x+=th[u].x; rh.y+=th[u].y; rh.z+=th[u].z; rh.w+=th[u].w;
      }
    }
    lo[(size_t)NSUP*64] = rl;     // grand totals
    hi[(size_t)NSUP*64] = rh;
  } else if (t < 192) {
    float4 z = {0,0,0,0};
    ((float4*)(Rel + ((size_t)b * NR1 + 4096) * 512))[t - 64] = z;
  } else if (t == 192) {
    float r = 0.f;
    for (int s = 0; s < NSUP; ++s) { float x = SupZlo[b*NS1+s]; SupZlo[b*NS1+s] = r; r += x; }
    SupZlo[b*NS1+NSUP] = r;
    Zrel[((size_t)b * NR1 + 4096) * 2] = 0.f;
  } else if (t == 193) {
    float r = 0.f;
    for (int s = 0; s < NSUP; ++s) { float x = SupZhi[b*NS1+s]; SupZhi[b*NS1+s] = r; r += x; }
    SupZhi[b*NS1+NSUP] = r;
    Zrel[((size_t)b * NR1 + 4096) * 2 + 1] = 0.f;
  }
}

// ---------------- K5: combine (binary search + gran-1 prefix) ------------------
__global__ __launch_bounds__(256) void k_combine2(const float* __restrict__ f1,
    const float* __restrict__ sF2, const float* __restrict__ Rel,
    const float* __restrict__ SupBaseLo, const float* __restrict__ SupBaseHi,
    const float* __restrict__ SupZlo, const float* __restrict__ SupZhi,
    const float* __restrict__ Zrel,
    const float* __restrict__ bias, float* __restrict__ out) {
  int wid = threadIdx.x >> 6, lane = threadIdx.x & 63;
  size_t i = (size_t)blockIdx.x * 4 + wid;
  int b = (int)(i >> 12);
  float f1v = f1[i];
  const float* sb = sF2 + ((size_t)b << 12);
  float t = -f1v;
  int lo = 0, hi = N;
  while (lo < hi) { int mid = (lo + hi) >> 1; if (sb[mid] <= t) lo = mid + 1; else hi = mid; }
  int k = lo;
  int s = k >> 6;
  float a = expf(f1v), cc = expf(0.01f * f1v);
  const float* rrow = Rel + ((size_t)b * NR1 + k) * 512;   // [d][2] interleaved
  float4 q0 = ((const float4*)rrow)[2*lane];      // lo0,hi0,lo1,hi1
  float4 q1 = ((const float4*)rrow)[2*lane + 1];  // lo2,hi2,lo3,hi3
  float4 sblo = ((const float4*)SupBaseLo)[((size_t)b * NS1 + s) * 64 + lane];
  float4 sbhi = ((const float4*)SupBaseHi)[((size_t)b * NS1 + s) * 64 + lane];
  float4 pht  = ((const float4*)SupBaseHi)[((size_t)b * NS1 + NSUP) * 64 + lane];
  float2 z2 = *(const float2*)(Zrel + ((size_t)b * NR1 + k) * 2);
  float Zlo = SupZlo[b*NS1+s] + z2.x;
  float Zhi = SupZhi[b*NS1+NSUP] - SupZhi[b*NS1+s] - z2.y;
  float Z = a * Zhi + cc * Zlo;
  float rz = 1.f / Z;
  float bs = bias[0];
  float4 o4;
  o4.x = fmaxf((a*(pht.x - sbhi.x - q0.y) + cc*(sblo.x + q0.x)) * rz + bs, 0.f);
  o4.y = fmaxf((a*(pht.y - sbhi.y - q0.w) + cc*(sblo.y + q0.z)) * rz + bs, 0.f);
  o4.z = fmaxf((a*(pht.z - sbhi.z - q1.y) + cc*(sblo.z + q1.x)) * rz + bs, 0.f);
  o4.w = fmaxf((a*(pht.w - sbhi.w - q1.w) + cc*(sblo.w + q1.z)) * rz + bs, 0.f);
  ((float4*)out)[i * 64 + lane] = o4;
}

// ---------------- launch -------------------------------------------------------
extern "C" void kernel_launch(void* const* d_in, const int* in_sizes, int n_in,
                              void* d_out, int out_size, void* d_ws, size_t ws_size,
                              hipStream_t stream) {
  const float* seq  = (const float*)d_in[0];
  const float* Wf   = (const float*)d_in[1];
  const float* w1   = (const float*)d_in[2];
  const float* b1   = (const float*)d_in[3];
  const float* w2   = (const float*)d_in[4];
  const float* b2   = (const float*)d_in[5];
  const float* bias = (const float*)d_in[6];
  float* out = (float*)d_out;

  size_t needFloats = (size_t)7*BN + (size_t)B*NR1*512 + 2*(size_t)B*NS1*D
                    + 2*(size_t)B*NS1 + 2*(size_t)B*NR1;
  size_t need = needFloats * 4 + (size_t)256 * 768 * 2;
  if (ws_size < need) return;

  float* f1   = (float*)d_ws;
  float* f2   = f1 + BN;
  float* sF2  = f2 + BN;
  float* e2lo = sF2 + BN;
  float* e2hi = e2lo + BN;
  int* sIdx   = (int*)(e2hi + BN);
  int* rank   = sIdx + BN;
  float* Rel  = (float*)(rank + BN);               // [b][k][d][2] interleaved
  float* SupBaseLo = Rel + (size_t)B * NR1 * 512;
  float* SupBaseHi = SupBaseLo + (size_t)B * NS1 * D;
  float* SupZlo = SupBaseHi + (size_t)B * NS1 * D;
  float* SupZhi = SupZlo + B * NS1;
  float* Zrel   = SupZhi + B * NS1;                // [b][k][2]
  ushort* W3 = (ushort*)(Zrel + 2 * (size_t)B * NR1);

  k_f1f2w<<<dim3(BN/4 + 256), 256, 0, stream>>>(seq, w1, b1, w2, b2, Wf,
      f1, f2, rank, W3);
  k_rank_count<<<dim3(N/1024, N/256, B), 256, 0, stream>>>(f2, rank);
  k_scatter<<<dim3(BN/256), 256, 0, stream>>>(f2, rank, sF2, sIdx, e2lo, e2hi);
  k_mfma<<<dim3(BN/64), 256, 0, stream>>>(seq, sIdx, W3, e2lo, e2hi,
      Rel, Zrel, SupBaseLo, SupBaseHi, SupZlo, SupZhi);
  k_supscan<<<dim3(B), 256, 0, stream>>>(SupBaseLo, SupBaseHi, SupZlo, SupZhi,
      Rel, Zrel);
  k_combine2<<<dim3(BN/4), 256, 0, stream>>>(f1, sF2, Rel,
      SupBaseLo, SupBaseHi, SupZlo, SupZhi, Zrel, bias, out);
}